// Round 22
// baseline (319.260 us; speedup 1.0000x reference)
//
#include <hip/hip_runtime.h>

#pragma clang fp contract(off)

#define BB 32
#define NN 8192
#define GG 256
#define KK 32

#define TFPS 512
#define JPF (NN / TFPS)  // 16 points per thread

// f32 max over a 16-lane row via DPP row_ror (pure VALU).
template <int CTRL>
__device__ __forceinline__ float rot_maxf(float v) {
  const int o =
      __builtin_amdgcn_update_dpp(0, __float_as_int(v), CTRL, 0xF, 0xF, true);
  return fmaxf(v, __int_as_float(o));
}

// ---------------- FPS: one block per batch, 512 threads (R7 verbatim) -----
__global__ __launch_bounds__(TFPS, 1) void fps_kernel(const float* __restrict__ xyz,
                                                      float* __restrict__ out) {
#pragma clang fp contract(off)
  const int b = blockIdx.x;
  const int t = threadIdx.x;
  const int lane = t & 63;
  const int wave = t >> 6;  // 0..7
  const float* __restrict__ P = xyz + (size_t)b * NN * 3;

  __shared__ float4 pts[NN];          // 128 KB: 1 ds_read_b128 per broadcast
  __shared__ float rowmax[2][32];     // 8 waves x 4 rows, double-buffered
  __shared__ unsigned winIdx[2];      // argmin-index slots, double-buffered

  float px[JPF], py[JPF], pz[JPF], md[JPF];
#pragma unroll
  for (int j = 0; j < JPF; ++j) {
    const int idx = t + j * TFPS;
    const float x = P[idx * 3 + 0];
    const float y = P[idx * 3 + 1];
    const float z = P[idx * 3 + 2];
    px[j] = x; py[j] = y; pz[j] = z;
    md[j] = __builtin_inff();
    pts[idx] = make_float4(x, y, z, 0.0f);
  }
  if (t == 0) { winIdx[0] = 0xFFFFFFFFu; winIdx[1] = 0xFFFFFFFFu; }
  __syncthreads();

  unsigned win = 0;      // first center = index 0
  unsigned mywin = 0;    // thread t<GG records the step-t winner

  for (int i = 0; i < GG; ++i) {
    if (t == i) mywin = win;
    if (i == GG - 1) break;

    // broadcast winner coords from LDS (single b128, uniform address)
    const float4 c = pts[win];
    const float cx = c.x, cy = c.y, cz = c.z;

    // distance update; track only the VALUE of the local max (no index ops)
    float bv = -1.0f;
#pragma unroll
    for (int j = 0; j < JPF; ++j) {
      const float dx = px[j] - cx;
      const float dy = py[j] - cy;
      const float dz = pz[j] - cz;
      const float d = dx * dx + dy * dy + dz * dz;  // ((x2+y2)+z2), no FMA
      const float m = md[j] < d ? md[j] : d;
      md[j] = m;
      bv = fmaxf(bv, m);
    }

    // level 1: 16-lane row max via DPP rotations (f32 only)
    float r = bv;
    r = rot_maxf<0x121>(r);  // ror 1
    r = rot_maxf<0x122>(r);  // ror 2
    r = rot_maxf<0x124>(r);  // ror 4
    r = rot_maxf<0x128>(r);  // ror 8
    if ((lane & 15) == 0)
      rowmax[i & 1][wave * 4 + (lane >> 4)] = r;
    __syncthreads();  // barrier 1

    // reset the OTHER buffer's index slot for step i+1
    if (t == 0) winIdx[(i + 1) & 1] = 0xFFFFFFFFu;

    // level 2: 32 row-maxes -> global max M in every lane (f32 only)
    const float* __restrict__ rm = rowmax[i & 1];
    const int g = lane & 15;
    float m2 = fmaxf(rm[g], rm[g + 16]);
    m2 = rot_maxf<0x121>(m2);
    m2 = rot_maxf<0x122>(m2);
    m2 = rot_maxf<0x124>(m2);
    m2 = rot_maxf<0x128>(m2);
    const float M = m2;

    // index recovery: only threads holding the max rescan (execz-skipped in
    // waves with no candidate); smallest global index wins (== first argmax)
    if (bv == M) {
      int fj = 0;
#pragma unroll
      for (int j = JPF - 1; j >= 0; --j)
        if (md[j] == M) fj = j;
      atomicMin(&winIdx[i & 1], (unsigned)t + ((unsigned)fj << 9));  // fj*512
    }
    __syncthreads();  // barrier 2

    win = winIdx[i & 1];
  }

  // write all centers once (off the critical loop)
  if (t < GG) {
    const float4 c = pts[mywin];
    float* __restrict__ co =
        out + (size_t)BB * GG * KK * 3 + ((size_t)b * GG + t) * 3;
    co[0] = c.x; co[1] = c.y; co[2] = c.z;
  }
}

// ---------------- KNN + gather: 8 blocks per batch ----------------
// float4 LDS staging (1 b128/point) + pass-1 fused across the wave's 4 groups.
__global__ __launch_bounds__(512, 1) void knn_kernel(const float* __restrict__ xyz,
                                                     float* __restrict__ out) {
#pragma clang fp contract(off)
  const int b = blockIdx.x >> 3;
  const int chunk = blockIdx.x & 7;
  const int t = threadIdx.x;
  const int lane = t & 63;
  const int wave = t >> 6;
  const float* __restrict__ P = xyz + (size_t)b * NN * 3;

  __shared__ float4 pts4[NN];                       // 128 KB
  __shared__ unsigned long long cand[8][256];       // 16 KB per-wave buffer

  for (int pt = t; pt < NN; pt += 512)
    pts4[pt] = make_float4(P[pt * 3 + 0], P[pt * 3 + 1], P[pt * 3 + 2], 0.0f);
  __syncthreads();

  const float* __restrict__ cent = out + (size_t)BB * GG * KK * 3;
  const int gbase = chunk * 32 + wave * 4;

  // load the wave's 4 centers into named scalars (compile-time indices only)
  const float c0x = cent[((size_t)b * GG + gbase + 0) * 3 + 0];
  const float c0y = cent[((size_t)b * GG + gbase + 0) * 3 + 1];
  const float c0z = cent[((size_t)b * GG + gbase + 0) * 3 + 2];
  const float c1x = cent[((size_t)b * GG + gbase + 1) * 3 + 0];
  const float c1y = cent[((size_t)b * GG + gbase + 1) * 3 + 1];
  const float c1z = cent[((size_t)b * GG + gbase + 1) * 3 + 2];
  const float c2x = cent[((size_t)b * GG + gbase + 2) * 3 + 0];
  const float c2y = cent[((size_t)b * GG + gbase + 2) * 3 + 1];
  const float c2z = cent[((size_t)b * GG + gbase + 2) * 3 + 2];
  const float c3x = cent[((size_t)b * GG + gbase + 3) * 3 + 0];
  const float c3y = cent[((size_t)b * GG + gbase + 3) * 3 + 1];
  const float c3z = cent[((size_t)b * GG + gbase + 3) * 3 + 2];

  // Pass 1 (fused): one sweep, 4 running minima
  float mn0 = __builtin_inff(), mn1 = __builtin_inff();
  float mn2 = __builtin_inff(), mn3 = __builtin_inff();
#pragma unroll 4
  for (int j = 0; j < 128; ++j) {
    const float4 p = pts4[lane + j * 64];
    {
      const float dx = p.x - c0x, dy = p.y - c0y, dz = p.z - c0z;
      mn0 = fminf(mn0, dx * dx + dy * dy + dz * dz);
    }
    {
      const float dx = p.x - c1x, dy = p.y - c1y, dz = p.z - c1z;
      mn1 = fminf(mn1, dx * dx + dy * dy + dz * dz);
    }
    {
      const float dx = p.x - c2x, dy = p.y - c2y, dz = p.z - c2z;
      mn2 = fminf(mn2, dx * dx + dy * dy + dz * dz);
    }
    {
      const float dx = p.x - c3x, dy = p.y - c3y, dz = p.z - c3z;
      mn3 = fminf(mn3, dx * dx + dy * dy + dz * dz);
    }
  }

  // threshold = 32nd-smallest of the 64 per-lane minima (+8 ulp guard)
  auto thresh = [&](float mn) -> float {
    float sm = mn;
#pragma unroll
    for (int k = 2; k <= 64; k <<= 1) {
#pragma unroll
      for (int j2 = k >> 1; j2 > 0; j2 >>= 1) {
        const float o = __shfl_xor(sm, j2, 64);
        const bool keepMin = (((lane & k) == 0) == ((lane & j2) == 0));
        sm = keepMin ? fminf(sm, o) : fmaxf(sm, o);
      }
    }
    const float v = __shfl(sm, 31, 64);
    return __uint_as_float(__float_as_uint(v) + 8);
  };
  const float vi0 = thresh(mn0);
  const float vi1 = thresh(mn1);
  const float vi2 = thresh(mn2);
  const float vi3 = thresh(mn3);

  // Pass 2 per group: recompute d2 (bit-identical), compact, sort, store
  auto dogroup = [&](int g, float cx, float cy, float cz, float vi) {
    unsigned cnt = 0;
    unsigned long long* __restrict__ cb = cand[wave];
#pragma unroll 4
    for (int j = 0; j < 128; ++j) {
      const int idx = lane + j * 64;
      const float4 p = pts4[idx];
      const float dx = p.x - cx, dy = p.y - cy, dz = p.z - cz;
      const float d2 = dx * dx + dy * dy + dz * dz;  // no FMA
      const bool pr = d2 <= vi;
      const unsigned long long mk = __ballot(pr);
      if (pr) {
        const unsigned off = cnt + (unsigned)__popcll(mk & ((1ull << lane) - 1));
        if (off < 256)
          cb[off] = ((unsigned long long)__float_as_uint(d2) << 32) |
                    (unsigned)idx;
      }
      cnt += (unsigned)__popcll(mk);
    }
    if (cnt > 256) cnt = 256;

    auto conv = [](unsigned long long e) -> unsigned long long {
      const float d = sqrtf(__uint_as_float((unsigned)(e >> 32)));
      return ((unsigned long long)__float_as_uint(d) << 32) | (e & 0xFFFFFFFFull);
    };

    unsigned long long myk;
    if (cnt <= 64) {
      unsigned long long key = ~0ull;
      if ((unsigned)lane < cnt) key = conv(cb[lane]);
#pragma unroll
      for (int k = 2; k <= 64; k <<= 1) {
#pragma unroll
        for (int j2 = k >> 1; j2 > 0; j2 >>= 1) {
          const unsigned long long o = __shfl_xor(key, j2, 64);
          const bool keepMin = (((lane & k) == 0) == ((lane & j2) == 0));
          const unsigned long long lo = o < key ? o : key;
          const unsigned long long hi = o < key ? key : o;
          key = keepMin ? lo : hi;
        }
      }
      myk = key;
    } else {
      // rare fallback: up to 256 candidates, 32 rounds of wave-argmin
      unsigned long long k0 = ~0ull, k1 = ~0ull, k2 = ~0ull, k3 = ~0ull;
      if ((unsigned)lane < cnt)         k0 = conv(cb[lane]);
      if ((unsigned)(lane + 64) < cnt)  k1 = conv(cb[lane + 64]);
      if ((unsigned)(lane + 128) < cnt) k2 = conv(cb[lane + 128]);
      if ((unsigned)(lane + 192) < cnt) k3 = conv(cb[lane + 192]);
      unsigned long long got = ~0ull;
      for (int r = 0; r < 32; ++r) {
        unsigned long long m01 = k0 < k1 ? k0 : k1;
        unsigned long long m23 = k2 < k3 ? k2 : k3;
        unsigned long long m = m01 < m23 ? m01 : m23;
#pragma unroll
        for (int s = 32; s > 0; s >>= 1) {
          const unsigned long long o = __shfl_xor(m, s, 64);
          m = o < m ? o : m;
        }
        if (lane == r) got = m;
        if (k0 == m) k0 = ~0ull;
        else if (k1 == m) k1 = ~0ull;
        else if (k2 == m) k2 = ~0ull;
        else if (k3 == m) k3 = ~0ull;
      }
      myk = got;
    }

    if (lane < KK) {
      const unsigned idx = (unsigned)(myk & 0xFFFFFFFFull);
      const float4 p = pts4[idx];
      float* __restrict__ po =
          out + ((size_t)(((size_t)b * GG + g) * KK + lane)) * 3;
      po[0] = p.x - cx; po[1] = p.y - cy; po[2] = p.z - cz;
    }
  };

  dogroup(gbase + 0, c0x, c0y, c0z, vi0);
  dogroup(gbase + 1, c1x, c1y, c1z, vi1);
  dogroup(gbase + 2, c2x, c2y, c2z, vi2);
  dogroup(gbase + 3, c3x, c3y, c3z, vi3);
}

extern "C" void kernel_launch(void* const* d_in, const int* in_sizes, int n_in,
                              void* d_out, int out_size, void* d_ws, size_t ws_size,
                              hipStream_t stream) {
  const float* xyz = (const float*)d_in[0];
  float* out = (float*)d_out;
  fps_kernel<<<dim3(BB), dim3(TFPS), 0, stream>>>(xyz, out);
  knn_kernel<<<dim3(BB * 8), dim3(512), 0, stream>>>(xyz, out);
}